// Round 3
// baseline (109.839 us; speedup 1.0000x reference)
//
#include <hip/hip_runtime.h>
#include <hip/hip_bf16.h>

#define B_   128
#define N_   65536
#define F_   512
#define CS   64                  // samples per chunk (per thread)
#define CPR  (N_ / CS)           // 1024 chunks per row
#define TPB  128                 // threads (=chunks) per block
#define CPB  TPB                 // chunks per block
#define BPR  (CPR / CPB)         // 8 blocks per row
#define NBLK (B_ * BPR)          // 1024 blocks
#define BLK_SAMP (TPB * CS)      // 8192 samples per block
#define KPOS ((float)(511.0 / 65535.0))
#define STRIDE 68                // padded LDS row stride (floats)

// ws layout (floats):
//   blockAgg  [NBLK][6]   : 6144 floats  (block-composed affine transform)
//   blockStart[NBLK][2]   : 2048 floats  (row-exact state at block start)
#define OFF_AGG   0
#define OFF_START (NBLK * 6)

__device__ __forceinline__ void load_acoef(const float* Lg, int i, float& a1, float& a2) {
    float l0 = Lg[i * 5 + 0], l1 = Lg[i * 5 + 1];
    a1 = 2.0f * tanhf(l0);
    float ab = fabsf(a1);
    a2 = 0.5f * ((2.0f - ab) * tanhf(l1) + ab);
}

// Kernel A: stage x -> LDS, compose per-chunk transforms, block-local scan,
// write ONE 6-float aggregate per block.
__global__ __launch_bounds__(TPB) void phaseA(const float* __restrict__ x,
                                              const float* __restrict__ logits,
                                              float* __restrict__ blockAgg) {
    __shared__ __align__(16) float buf[TPB][STRIDE];
    __shared__ float sc[6][TPB];
    int tid = threadIdx.x;
    int gchunk0 = blockIdx.x * TPB;

    const float4* xg = (const float4*)x + (size_t)gchunk0 * (CS / 4);
    #pragma unroll
    for (int it = 0; it < BLK_SAMP / 4 / TPB; ++it) {
        int i4 = it * TPB + tid;
        float4 v = xg[i4];
        *(float4*)&buf[i4 >> 4][(i4 & 15) * 4] = v;
    }
    __syncthreads();

    int t = gchunk0 + tid;
    int b = t >> 10;
    int c = t & (CPR - 1);
    int n0 = c * CS;

    int I  = min((int)floorf((float)n0 * KPOS), F_ - 2);
    int I2 = min(I + 2, F_ - 1);
    const float* Lg = logits + (size_t)b * F_ * 5;
    float a1A, a2A, a1B, a2B, a1C, a2C;
    load_acoef(Lg, I,     a1A, a2A);
    load_acoef(Lg, I + 1, a1B, a2B);
    load_acoef(Lg, I2,    a1C, a2C);

    float A00 = 1.f, A01 = 0.f, A10 = 0.f, A11 = 1.f, v0 = 0.f, v1 = 0.f;
    #pragma unroll 4
    for (int j = 0; j < CS / 4; ++j) {
        float4 xv = *(const float4*)&buf[tid][j * 4];
        #pragma unroll
        for (int u = 0; u < 4; ++u) {
            int k = j * 4 + u;
            float xn = (&xv.x)[u];
            float pos = (float)(n0 + k) * KPOS;
            int i0 = min((int)floorf(pos), F_ - 2);
            float frac = pos - (float)i0;
            float om = 1.0f - frac;
            bool sel = i0 > I;
            float a1 = om * (sel ? a1B : a1A) + frac * (sel ? a1C : a1B);
            float a2 = om * (sel ? a2B : a2A) + frac * (sel ? a2C : a2B);
            float nA00 = -a1 * A00 - a2 * A10;
            float nA01 = -a1 * A01 - a2 * A11;
            float nv0  = xn - a1 * v0 - a2 * v1;
            A10 = A00; A11 = A01; v1 = v0;
            A00 = nA00; A01 = nA01; v0 = nv0;
        }
    }

    // block-local inclusive Hillis-Steele scan over CPB chunk transforms
    for (int d = 1; d < TPB; d <<= 1) {
        sc[0][tid] = A00; sc[1][tid] = A01; sc[2][tid] = A10;
        sc[3][tid] = A11; sc[4][tid] = v0;  sc[5][tid] = v1;
        __syncthreads();
        if (tid >= d) {
            float f00 = sc[0][tid - d], f01 = sc[1][tid - d];
            float f10 = sc[2][tid - d], f11 = sc[3][tid - d];
            float fv0 = sc[4][tid - d], fv1 = sc[5][tid - d];
            float n00 = A00 * f00 + A01 * f10;
            float n01 = A00 * f01 + A01 * f11;
            float n10 = A10 * f00 + A11 * f10;
            float n11 = A10 * f01 + A11 * f11;
            float nv0 = A00 * fv0 + A01 * fv1 + v0;
            float nv1 = A10 * fv0 + A11 * fv1 + v1;
            A00 = n00; A01 = n01; A10 = n10; A11 = n11; v0 = nv0; v1 = nv1;
        }
        __syncthreads();
    }
    if (tid == TPB - 1) {
        float* T = blockAgg + (size_t)blockIdx.x * 6;
        T[0] = A00; T[1] = A01; T[2] = A10; T[3] = A11; T[4] = v0; T[5] = v1;
    }
}

// Kernel B: per row, serially compose the 8 block aggregates -> block start states.
__global__ __launch_bounds__(TPB) void phaseB(const float* __restrict__ blockAgg,
                                              float* __restrict__ blockStart) {
    int r = threadIdx.x;   // one thread per row, single block of 128
    float s0 = 0.f, s1 = 0.f;
    #pragma unroll
    for (int j = 0; j < BPR; ++j) {
        int g = r * BPR + j;
        blockStart[g * 2 + 0] = s0;
        blockStart[g * 2 + 1] = s1;
        const float* T = blockAgg + (size_t)g * 6;
        float n0 = T[0] * s0 + T[1] * s1 + T[4];
        float n1 = T[2] * s0 + T[3] * s1 + T[5];
        s0 = n0; s1 = n1;
    }
}

// Kernel C: re-stage x, recompose transforms, block-local scan -> per-chunk
// exclusive prefix, apply block start state, run recurrence + fused FIR, write out.
__global__ __launch_bounds__(TPB) void phaseC(const float* __restrict__ x,
                                              const float* __restrict__ logits,
                                              const float* __restrict__ blockStart,
                                              float* __restrict__ out) {
    __shared__ __align__(16) float buf[TPB][STRIDE];
    __shared__ float sc[6][TPB];
    int tid = threadIdx.x;
    int gchunk0 = blockIdx.x * TPB;

    const float4* xg = (const float4*)x + (size_t)gchunk0 * (CS / 4);
    #pragma unroll
    for (int it = 0; it < BLK_SAMP / 4 / TPB; ++it) {
        int i4 = it * TPB + tid;
        float4 v = xg[i4];
        *(float4*)&buf[i4 >> 4][(i4 & 15) * 4] = v;
    }
    __syncthreads();

    int t = gchunk0 + tid;
    int b = t >> 10;
    int c = t & (CPR - 1);
    int n0 = c * CS;

    int I  = min((int)floorf((float)n0 * KPOS), F_ - 2);
    int I2 = min(I + 2, F_ - 1);
    const float* Lg = logits + (size_t)b * F_ * 5;
    float cA[5], cB[5], cC[5];
    load_acoef(Lg, I,     cA[0], cA[1]);
    load_acoef(Lg, I + 1, cB[0], cB[1]);
    load_acoef(Lg, I2,    cC[0], cC[1]);
    #pragma unroll
    for (int j = 0; j < 3; ++j) {
        cA[2 + j] = Lg[I * 5 + 2 + j];
        cB[2 + j] = Lg[(I + 1) * 5 + 2 + j];
        cC[2 + j] = Lg[I2 * 5 + 2 + j];
    }

    // recompose this chunk's transform (a-coeffs only)
    float A00 = 1.f, A01 = 0.f, A10 = 0.f, A11 = 1.f, v0 = 0.f, v1 = 0.f;
    #pragma unroll 4
    for (int j = 0; j < CS / 4; ++j) {
        float4 xv = *(const float4*)&buf[tid][j * 4];
        #pragma unroll
        for (int u = 0; u < 4; ++u) {
            int k = j * 4 + u;
            float xn = (&xv.x)[u];
            float pos = (float)(n0 + k) * KPOS;
            int i0 = min((int)floorf(pos), F_ - 2);
            float frac = pos - (float)i0;
            float om = 1.0f - frac;
            bool sel = i0 > I;
            float a1 = om * (sel ? cB[0] : cA[0]) + frac * (sel ? cC[0] : cB[0]);
            float a2 = om * (sel ? cB[1] : cA[1]) + frac * (sel ? cC[1] : cB[1]);
            float nA00 = -a1 * A00 - a2 * A10;
            float nA01 = -a1 * A01 - a2 * A11;
            float nv0  = xn - a1 * v0 - a2 * v1;
            A10 = A00; A11 = A01; v1 = v0;
            A00 = nA00; A01 = nA01; v0 = nv0;
        }
    }

    // block-local inclusive scan
    for (int d = 1; d < TPB; d <<= 1) {
        sc[0][tid] = A00; sc[1][tid] = A01; sc[2][tid] = A10;
        sc[3][tid] = A11; sc[4][tid] = v0;  sc[5][tid] = v1;
        __syncthreads();
        if (tid >= d) {
            float f00 = sc[0][tid - d], f01 = sc[1][tid - d];
            float f10 = sc[2][tid - d], f11 = sc[3][tid - d];
            float fv0 = sc[4][tid - d], fv1 = sc[5][tid - d];
            float n00 = A00 * f00 + A01 * f10;
            float n01 = A00 * f01 + A01 * f11;
            float n10 = A10 * f00 + A11 * f10;
            float n11 = A10 * f01 + A11 * f11;
            float nv0 = A00 * fv0 + A01 * fv1 + v0;
            float nv1 = A10 * fv0 + A11 * fv1 + v1;
            A00 = n00; A01 = n01; A10 = n10; A11 = n11; v0 = nv0; v1 = nv1;
        }
        __syncthreads();
    }
    // publish inclusive results; thread c's exclusive prefix = inclusive[c-1]
    sc[0][tid] = A00; sc[1][tid] = A01; sc[2][tid] = A10;
    sc[3][tid] = A11; sc[4][tid] = v0;  sc[5][tid] = v1;
    __syncthreads();

    float bs0 = blockStart[(size_t)blockIdx.x * 2 + 0];
    float bs1 = blockStart[(size_t)blockIdx.x * 2 + 1];
    float s0v, s1v;
    if (tid == 0) {
        s0v = bs0; s1v = bs1;
    } else {
        float L00 = sc[0][tid - 1], L01 = sc[1][tid - 1];
        float L10 = sc[2][tid - 1], L11 = sc[3][tid - 1];
        float Lv0 = sc[4][tid - 1], Lv1 = sc[5][tid - 1];
        s0v = L00 * bs0 + L01 * bs1 + Lv0;
        s1v = L10 * bs0 + L11 * bs1 + Lv1;
    }
    __syncthreads();   // done reading sc before anything else (none) — safe ordering

    // recurrence from exact start state + fused FIR; overwrite own LDS row with y
    #pragma unroll 4
    for (int j = 0; j < CS / 4; ++j) {
        float4 xv = *(const float4*)&buf[tid][j * 4];
        float4 yv;
        #pragma unroll
        for (int u = 0; u < 4; ++u) {
            int k = j * 4 + u;
            float xn = (&xv.x)[u];
            float pos = (float)(n0 + k) * KPOS;
            int i0 = min((int)floorf(pos), F_ - 2);
            float frac = pos - (float)i0;
            float om = 1.0f - frac;
            bool sel = i0 > I;
            float a1 = om * (sel ? cB[0] : cA[0]) + frac * (sel ? cC[0] : cB[0]);
            float a2 = om * (sel ? cB[1] : cA[1]) + frac * (sel ? cC[1] : cB[1]);
            float b0 = om * (sel ? cB[2] : cA[2]) + frac * (sel ? cC[2] : cB[2]);
            float b1 = om * (sel ? cB[3] : cA[3]) + frac * (sel ? cC[3] : cB[3]);
            float b2 = om * (sel ? cB[4] : cA[4]) + frac * (sel ? cC[4] : cB[4]);
            float y = xn - a1 * s0v - a2 * s1v;
            (&yv.x)[u] = b0 * y + b1 * s0v + b2 * s1v;
            s1v = s0v; s0v = y;
        }
        *(float4*)&buf[tid][j * 4] = yv;
    }
    __syncthreads();

    float4* og = (float4*)out + (size_t)gchunk0 * (CS / 4);
    #pragma unroll
    for (int it = 0; it < BLK_SAMP / 4 / TPB; ++it) {
        int i4 = it * TPB + tid;
        og[i4] = *(float4*)&buf[i4 >> 4][(i4 & 15) * 4];
    }
}

extern "C" void kernel_launch(void* const* d_in, const int* in_sizes, int n_in,
                              void* d_out, int out_size, void* d_ws, size_t ws_size,
                              hipStream_t stream) {
    const float* x      = (const float*)d_in[0];   // (B, N) f32
    const float* logits = (const float*)d_in[1];   // (B, F, 5) f32
    float* out = (float*)d_out;                    // (B, N) f32
    float* ws  = (float*)d_ws;

    float* blockAgg   = ws + OFF_AGG;
    float* blockStart = ws + OFF_START;

    phaseA<<<NBLK, TPB, 0, stream>>>(x, logits, blockAgg);
    phaseB<<<1, TPB, 0, stream>>>(blockAgg, blockStart);
    phaseC<<<NBLK, TPB, 0, stream>>>(x, logits, blockStart, out);
}

// Round 5
// 100.995 us; speedup vs baseline: 1.0876x; 1.0876x over previous
//
#include <hip/hip_runtime.h>
#include <hip/hip_bf16.h>

#define B_   128
#define N_   65536
#define F_   512
#define CS   64                  // samples per chunk (per thread)
#define CPR  (N_ / CS)           // 1024 chunks per row
#define TPB  128                 // threads (=chunks) per block
#define BPR  (CPR / TPB)         // 8 blocks per row
#define NBLK (B_ * BPR)          // 1024 blocks
#define BLK_SAMP (TPB * CS)      // 8192 samples per block
#define NT   (B_ * CPR)          // 131072 chunks total
#define KPOS ((float)(511.0 / 65535.0))
#define INVK ((float)(65535.0 / 511.0))
#define STRIDE 68                // padded LDS row stride (floats); 17 float4-groups -> conflict-free

// ws layout (floats):
//   pref [6][NT]   : per-chunk exclusive block-local prefix (SoA, coalesced)
//   agg  [NBLK][6] : per-block aggregate transform (AoS, read by single threads)
#define OFF_PREF 0
#define OFF_AGG  (6 * NT)

__device__ __forceinline__ float tanh_map1(float l) { return 2.0f * tanhf(l); }

// Compute chunk geometry: I (i0 at chunk start), kc (first sample index whose
// i0 is I+1; 64 if no crossing), exactly matching reference floorf((n0+k)*K).
__device__ __forceinline__ void chunk_geom(int n0, float& pos0, int& I, int& kc) {
    pos0 = (float)n0 * KPOS;
    I = min((int)pos0, F_ - 2);
    int k = (int)ceilf(((float)(I + 1) - pos0) * INVK);
    k = max(0, min(k, CS));
    // fix rounding against reference arithmetic
    if (k > 0 && (int)((float)(n0 + k - 1) * KPOS) > I) --k;
    else if (k < CS && (int)((float)(n0 + k) * KPOS) <= I) ++k;
    if ((int)pos0 > F_ - 2) k = CS;          // fully clipped: never switch segment
    if (I == F_ - 2) {
        // if pos0 already at/above the last knee, no segment switch possible
        if ((float)n0 * KPOS >= (float)(F_ - 1)) k = CS;
    }
    kc = k;
}

// Kernel A: stage x -> LDS, compose per-chunk transforms, block-local scan.
// Persists per-chunk EXCLUSIVE local prefixes (SoA) + one aggregate per block.
__global__ __launch_bounds__(TPB, 2) void phaseA(const float* __restrict__ x,
                                                 const float* __restrict__ logits,
                                                 float* __restrict__ pref,
                                                 float* __restrict__ agg) {
    __shared__ __align__(16) float buf[TPB][STRIDE];
    __shared__ float sc[6][TPB];
    int tid = threadIdx.x;
    int gid = blockIdx.x;
    int gchunk0 = gid * TPB;

    const float4* xg = (const float4*)x + (size_t)gchunk0 * (CS / 4);
    #pragma unroll
    for (int it = 0; it < BLK_SAMP / 4 / TPB; ++it) {
        int i4 = it * TPB + tid;
        float4 v = xg[i4];
        *(float4*)&buf[i4 >> 4][(i4 & 15) * 4] = v;
    }
    __syncthreads();

    int t = gchunk0 + tid;
    int b = t >> 10;
    int c = t & (CPR - 1);
    int n0 = c * CS;

    float pos0; int I, kc;
    chunk_geom(n0, pos0, I, kc);
    int I2 = min(I + 2, F_ - 1);
    const float* Lg = logits + (size_t)b * F_ * 5;
    float a1A = tanh_map1(Lg[I * 5 + 0]);
    float a1B = tanh_map1(Lg[(I + 1) * 5 + 0]);
    float a1C = tanh_map1(Lg[I2 * 5 + 0]);
    float t1A = tanhf(Lg[I * 5 + 1]);
    float t1B = tanhf(Lg[(I + 1) * 5 + 1]);
    float t1C = tanhf(Lg[I2 * 5 + 1]);
    float a2A = 0.5f * ((2.0f - fabsf(a1A)) * t1A + fabsf(a1A));
    float a2B = 0.5f * ((2.0f - fabsf(a1B)) * t1B + fabsf(a1B));
    float a2C = 0.5f * ((2.0f - fabsf(a1C)) * t1C + fabsf(a1C));

    float If = (float)I;
    float C1  = fmaf(pos0 - If,        a1B - a1A, a1A), D1  = KPOS * (a1B - a1A);
    float C1b = fmaf(pos0 - If - 1.f,  a1C - a1B, a1B), D1b = KPOS * (a1C - a1B);
    float C2  = fmaf(pos0 - If,        a2B - a2A, a2A), D2  = KPOS * (a2B - a2A);
    float C2b = fmaf(pos0 - If - 1.f,  a2C - a2B, a2B), D2b = KPOS * (a2C - a2B);

    float A00 = 1.f, A01 = 0.f, A10 = 0.f, A11 = 1.f, v0 = 0.f, v1 = 0.f;
    #pragma unroll
    for (int j = 0; j < CS / 4; ++j) {
        float4 xv = *(const float4*)&buf[tid][j * 4];
        #pragma unroll
        for (int u = 0; u < 4; ++u) {
            int k = j * 4 + u;
            float xn = (&xv.x)[u];
            bool sB = (k >= kc);
            float kf = (float)k;
            float a1 = fmaf(kf, sB ? D1b : D1, sB ? C1b : C1);
            float a2 = fmaf(kf, sB ? D2b : D2, sB ? C2b : C2);
            float nA00 = fmaf(-a2, A10, -a1 * A00);
            float nA01 = fmaf(-a2, A11, -a1 * A01);
            float nv0  = fmaf(-a2, v1, fmaf(-a1, v0, xn));
            A10 = A00; A11 = A01; v1 = v0;
            A00 = nA00; A01 = nA01; v0 = nv0;
        }
    }

    // block-local inclusive Hillis-Steele scan
    for (int d = 1; d < TPB; d <<= 1) {
        sc[0][tid] = A00; sc[1][tid] = A01; sc[2][tid] = A10;
        sc[3][tid] = A11; sc[4][tid] = v0;  sc[5][tid] = v1;
        __syncthreads();
        if (tid >= d) {
            float f00 = sc[0][tid - d], f01 = sc[1][tid - d];
            float f10 = sc[2][tid - d], f11 = sc[3][tid - d];
            float fv0 = sc[4][tid - d], fv1 = sc[5][tid - d];
            float n00 = A00 * f00 + A01 * f10;
            float n01 = A00 * f01 + A01 * f11;
            float n10 = A10 * f00 + A11 * f10;
            float n11 = A10 * f01 + A11 * f11;
            float nv0 = A00 * fv0 + A01 * fv1 + v0;
            float nv1 = A10 * fv0 + A11 * fv1 + v1;
            A00 = n00; A01 = n01; A10 = n10; A11 = n11; v0 = nv0; v1 = nv1;
        }
        __syncthreads();
    }
    sc[0][tid] = A00; sc[1][tid] = A01; sc[2][tid] = A10;
    sc[3][tid] = A11; sc[4][tid] = v0;  sc[5][tid] = v1;
    __syncthreads();

    float e00, e01, e10, e11, ev0, ev1;
    if (tid == 0) { e00 = 1.f; e01 = 0.f; e10 = 0.f; e11 = 1.f; ev0 = 0.f; ev1 = 0.f; }
    else {
        e00 = sc[0][tid - 1]; e01 = sc[1][tid - 1];
        e10 = sc[2][tid - 1]; e11 = sc[3][tid - 1];
        ev0 = sc[4][tid - 1]; ev1 = sc[5][tid - 1];
    }
    pref[0 * NT + t] = e00; pref[1 * NT + t] = e01;
    pref[2 * NT + t] = e10; pref[3 * NT + t] = e11;
    pref[4 * NT + t] = ev0; pref[5 * NT + t] = ev1;
    if (tid == TPB - 1) {
        float* T = agg + (size_t)gid * 6;
        T[0] = A00; T[1] = A01; T[2] = A10; T[3] = A11; T[4] = v0; T[5] = v1;
    }
}

// Kernel C: no compose, no scan. Fold preceding block aggregates (thread 0),
// apply per-chunk exclusive prefix, run recurrence + fused FIR, write out.
__global__ __launch_bounds__(TPB, 2) void phaseC(const float* __restrict__ x,
                                                 const float* __restrict__ logits,
                                                 const float* __restrict__ pref,
                                                 const float* __restrict__ agg,
                                                 float* __restrict__ out) {
    __shared__ __align__(16) float buf[TPB][STRIDE];
    __shared__ float sbs[2];
    int tid = threadIdx.x;
    int gid = blockIdx.x;
    int gchunk0 = gid * TPB;

    const float4* xg = (const float4*)x + (size_t)gchunk0 * (CS / 4);
    #pragma unroll
    for (int it = 0; it < BLK_SAMP / 4 / TPB; ++it) {
        int i4 = it * TPB + tid;
        float4 v = xg[i4];
        *(float4*)&buf[i4 >> 4][(i4 & 15) * 4] = v;
    }

    if (tid == 0) {
        float s0 = 0.f, s1 = 0.f;
        int p0 = gid & ~(BPR - 1);
        for (int p = p0; p < gid; ++p) {
            const float* T = agg + (size_t)p * 6;
            float n0s = T[0] * s0 + T[1] * s1 + T[4];
            float n1s = T[2] * s0 + T[3] * s1 + T[5];
            s0 = n0s; s1 = n1s;
        }
        sbs[0] = s0; sbs[1] = s1;
    }

    int t = gchunk0 + tid;
    int b = t >> 10;
    int c = t & (CPR - 1);
    int n0 = c * CS;

    float pos0; int I, kc;
    chunk_geom(n0, pos0, I, kc);
    int I2 = min(I + 2, F_ - 1);
    const float* Lg = logits + (size_t)b * F_ * 5;
    float vA[5], vB[5], vC[5];
    {
        float a1A = tanh_map1(Lg[I * 5 + 0]);
        float a1B = tanh_map1(Lg[(I + 1) * 5 + 0]);
        float a1C = tanh_map1(Lg[I2 * 5 + 0]);
        float t1A = tanhf(Lg[I * 5 + 1]);
        float t1B = tanhf(Lg[(I + 1) * 5 + 1]);
        float t1C = tanhf(Lg[I2 * 5 + 1]);
        vA[0] = a1A; vB[0] = a1B; vC[0] = a1C;
        vA[1] = 0.5f * ((2.0f - fabsf(a1A)) * t1A + fabsf(a1A));
        vB[1] = 0.5f * ((2.0f - fabsf(a1B)) * t1B + fabsf(a1B));
        vC[1] = 0.5f * ((2.0f - fabsf(a1C)) * t1C + fabsf(a1C));
        #pragma unroll
        for (int j = 0; j < 3; ++j) {
            vA[2 + j] = Lg[I * 5 + 2 + j];
            vB[2 + j] = Lg[(I + 1) * 5 + 2 + j];
            vC[2 + j] = Lg[I2 * 5 + 2 + j];
        }
    }
    float If = (float)I;
    float Cs[5], Ds[5], Csb[5], Dsb[5];
    #pragma unroll
    for (int j = 0; j < 5; ++j) {
        Cs[j]  = fmaf(pos0 - If,       vB[j] - vA[j], vA[j]);
        Ds[j]  = KPOS * (vB[j] - vA[j]);
        Csb[j] = fmaf(pos0 - If - 1.f, vC[j] - vB[j], vB[j]);
        Dsb[j] = KPOS * (vC[j] - vB[j]);
    }

    // own exclusive block-local prefix
    float L00 = pref[0 * NT + t], L01 = pref[1 * NT + t];
    float L10 = pref[2 * NT + t], L11 = pref[3 * NT + t];
    float Lv0 = pref[4 * NT + t], Lv1 = pref[5 * NT + t];

    __syncthreads();   // covers x staging + sbs

    float bs0 = sbs[0], bs1 = sbs[1];
    float s0v = L00 * bs0 + L01 * bs1 + Lv0;   // y[n0-1]
    float s1v = L10 * bs0 + L11 * bs1 + Lv1;   // y[n0-2]

    #pragma unroll
    for (int j = 0; j < CS / 4; ++j) {
        float4 xv = *(const float4*)&buf[tid][j * 4];
        float4 yv;
        #pragma unroll
        for (int u = 0; u < 4; ++u) {
            int k = j * 4 + u;
            float xn = (&xv.x)[u];
            bool sB = (k >= kc);
            float kf = (float)k;
            float a1 = fmaf(kf, sB ? Dsb[0] : Ds[0], sB ? Csb[0] : Cs[0]);
            float a2 = fmaf(kf, sB ? Dsb[1] : Ds[1], sB ? Csb[1] : Cs[1]);
            float b0 = fmaf(kf, sB ? Dsb[2] : Ds[2], sB ? Csb[2] : Cs[2]);
            float b1 = fmaf(kf, sB ? Dsb[3] : Ds[3], sB ? Csb[3] : Cs[3]);
            float b2 = fmaf(kf, sB ? Dsb[4] : Ds[4], sB ? Csb[4] : Cs[4]);
            float y = fmaf(-a2, s1v, fmaf(-a1, s0v, xn));
            (&yv.x)[u] = fmaf(b2, s1v, fmaf(b1, s0v, b0 * y));
            s1v = s0v; s0v = y;
        }
        *(float4*)&buf[tid][j * 4] = yv;
    }
    __syncthreads();

    float4* og = (float4*)out + (size_t)gchunk0 * (CS / 4);
    #pragma unroll
    for (int it = 0; it < BLK_SAMP / 4 / TPB; ++it) {
        int i4 = it * TPB + tid;
        og[i4] = *(float4*)&buf[i4 >> 4][(i4 & 15) * 4];
    }
}

extern "C" void kernel_launch(void* const* d_in, const int* in_sizes, int n_in,
                              void* d_out, int out_size, void* d_ws, size_t ws_size,
                              hipStream_t stream) {
    const float* x      = (const float*)d_in[0];   // (B, N) f32
    const float* logits = (const float*)d_in[1];   // (B, F, 5) f32
    float* out = (float*)d_out;                    // (B, N) f32
    float* ws  = (float*)d_ws;

    float* pref = ws + OFF_PREF;
    float* agg  = ws + OFF_AGG;

    phaseA<<<NBLK, TPB, 0, stream>>>(x, logits, pref, agg);
    phaseC<<<NBLK, TPB, 0, stream>>>(x, logits, pref, agg, out);
}